// Round 15
// baseline (113.021 us; speedup 1.0000x reference)
//
#include <hip/hip_runtime.h>
#include <hip/hip_fp16.h>

// SoftMorphology soft-skeleton: columns-in-registers stencil, f16, DPP.
// Round-15 = round-13 structure (RV=8, zero arrays, packed-f16 state, DPP
// lane shifts, f16 handoffs) split over THREE launches (S=4,4,3) instead
// of two (6,5):
//  * R = RV+2*(S+1) = 18/18/16 rows -> F 36 regs + Q 16 ~= 60 VGPR total,
//    under the 64-VGPR occupancy cliff (r13: 68 -> 4 waves/SIMD; <=64 ->
//    8 waves/SIMD, 2x latency hiding; r11-r14 show the kernel is
//    VALU-issue-bound with 27% latency exposure).
//  * total pipeline steps per 8 output rows: 160 -> 140 (-12.5%).
//  * cost: one extra E+q round-trip (+64MB HBM, hidden under compute at
//    27% HBM util) + one launch overhead.
// q16 updated IN-PLACE across launches: q never crosses lanes; halo-lane
// q reads may race with neighbor-block writes but are discarded (only wr
// lanes stored). E-levels ping between separate buffers (halo reads of E
// are real dependencies -> no in-place).
// Verified-invariant algorithm (r5-r14): erode = min 5-pt cross, dilate =
// max 3x3 (selection ops => f16-exact); q = 1-s, q *= 1-relu(pm-dd).
// Borders: clamped loads = replicate guards absorbed by erode; dilate
// exact via mL/mR lane overrides + top/bot h-row swaps; DPP invalid-lane
// zeros land in the region-edge contamination margin (<=1 col/stage,
// col halo 8 >= S+1=5).

#define W 1024
#define H 1024
#define NBATCH 16
#define RV 8

__device__ __forceinline__ uint32_t HMIN2(uint32_t a, uint32_t b) {
  uint32_t d;
  asm("v_pk_min_f16 %0, %1, %2" : "=v"(d) : "v"(a), "v"(b));
  return d;
}
__device__ __forceinline__ uint32_t HMAX2(uint32_t a, uint32_t b) {
  uint32_t d;
  asm("v_pk_max_f16 %0, %1, %2" : "=v"(d) : "v"(a), "v"(b));
  return d;
}
__device__ __forceinline__ uint32_t PKSUB(uint32_t a, uint32_t b) {
  uint32_t d;  // a - b (packed f16)
  asm("v_pk_add_f16 %0, %1, %2 neg_lo:[0,1] neg_hi:[0,1]"
      : "=v"(d) : "v"(a), "v"(b));
  return d;
}
__device__ __forceinline__ uint32_t PKMUL(uint32_t a, uint32_t b) {
  uint32_t d;
  asm("v_pk_mul_f16 %0, %1, %2" : "=v"(d) : "v"(a), "v"(b));
  return d;
}
__device__ __forceinline__ uint32_t PKRELU(uint32_t a) {
  uint32_t d;  // max(a, 0) packed
  asm("v_pk_max_f16 %0, %1, 0" : "=v"(d) : "v"(a));
  return d;
}
__device__ __forceinline__ uint32_t PK(float x, float y) {
  __half2 h = __floats2half2_rn(x, y);
  return *(uint32_t*)&h;
}
__device__ __forceinline__ float CVTLO(uint32_t u) {
  uint16_t t = (uint16_t)(u & 0xffffu);
  __half h = *(__half*)&t;
  return __half2float(h);
}
__device__ __forceinline__ float CVTHI(uint32_t u) {
  uint16_t t = (uint16_t)(u >> 16);
  __half h = *(__half*)&t;
  return __half2float(h);
}
// DPP wave shifts: lane i <- lane i-1 (SHUP) / lane i+1 (SHDN); invalid
// lane gets 0 (bound_ctrl) -- lands in halo contamination zone only.
__device__ __forceinline__ uint32_t SHUP(uint32_t x) {  // wave_shr:1
  return (uint32_t)__builtin_amdgcn_update_dpp(0, (int)x, 0x138, 0xf, 0xf,
                                               true);
}
__device__ __forceinline__ uint32_t SHDN(uint32_t x) {  // wave_shl:1
  return (uint32_t)__builtin_amdgcn_update_dpp(0, (int)x, 0x130, 0xf, 0xf,
                                               true);
}

// One pipeline step i (P,C,N = i-1,i,i+1): erode (row P <- min-cross of
// PM,C,N), rolling h-max, packed-f16 skel-q update for row K.
#define STEP(P, C, N, DOH, DOU, K, INIT) {                                  \
  const uint32_t ca = F##C##a, cb = F##C##b;                                \
  const uint32_t na = F##N##a, nb = F##N##b;                                \
  const uint32_t vma = HMIN2(HMIN2(PMa, ca), na);                           \
  const uint32_t vmb = HMIN2(HMIN2(PMb, cb), nb);                           \
  const uint32_t t = SHUP(cb);                                              \
  const uint32_t r = SHDN(ca);                                              \
  const uint32_t m1 = mL ? (ca & 0xffffu) : (t >> 16);                      \
  const uint32_t r4 = mR ? (cb >> 16) : (r & 0xffffu);                      \
  const uint32_t sla = (ca >> 16) | (cb << 16);                             \
  const uint32_t slb = (cb >> 16) | (r4 << 16);                             \
  const uint32_t sra = m1 | (ca << 16);                                     \
  const uint32_t ea = HMIN2(vma, HMIN2(sra, sla));                          \
  const uint32_t eb = HMIN2(vmb, HMIN2(sla, slb));                          \
  if (DOH) {                                                                \
    const uint32_t te = SHUP(eb);                                           \
    const uint32_t re = SHDN(ea);                                           \
    const uint32_t em1 = mL ? (ea & 0xffffu) : (te >> 16);                  \
    const uint32_t er4 = mR ? (eb >> 16) : (re & 0xffffu);                  \
    const uint32_t esla = (ea >> 16) | (eb << 16);                          \
    const uint32_t eslb = (eb >> 16) | (er4 << 16);                         \
    const uint32_t esra = em1 | (ea << 16);                                 \
    const uint32_t hca = HMAX2(ea, HMAX2(esra, esla));                      \
    const uint32_t hcb = HMAX2(eb, HMAX2(esla, eslb));                      \
    if (DOU) {                                                              \
      uint32_t haa = h2a, hab = h2b, hba = hca, hbb = hcb;                  \
      if (K == 0 && top) { haa = h1a; hab = h1b; }                          \
      if (K == RV - 1 && bot) { hba = h1a; hbb = h1b; }                     \
      const uint32_t dda = HMAX2(HMAX2(haa, h1a), hba);                     \
      const uint32_t ddb = HMAX2(HMAX2(hab, h1b), hbb);                     \
      const uint32_t fa = PKSUB(ONE2, PKRELU(PKSUB(PMa, dda)));             \
      const uint32_t fb = PKSUB(ONE2, PKRELU(PKSUB(PMb, ddb)));             \
      if (INIT) { Q##K##a = fa; Q##K##b = fb; }                             \
      else { Q##K##a = PKMUL(Q##K##a, fa); Q##K##b = PKMUL(Q##K##b, fb); }  \
    }                                                                       \
    h2a = h1a; h2b = h1b; h1a = hca; h1b = hcb;                             \
  }                                                                         \
  F##P##a = ea; F##P##b = eb;                                               \
  PMa = ca; PMb = cb;                                                       \
}

#define STAGE_BEGIN uint32_t PMa = F0a, PMb = F0b,                          \
    h1a = 0, h1b = 0, h2a = 0, h2b = 0;

// RV=8 stage bodies by valid-row count V; HT = (V-RV-2)/2 = HALO-T.
// DOH i in [HT, HT+RV+1], DOU i in [HT+2, HT+RV+1], K = i-2-HT.
// (STEP(P,C,N) is step i = P+1.)
#define S_V18(INIT) { STAGE_BEGIN                                           \
  STEP(0,1,2,0,0,0,INIT)   STEP(1,2,3,0,0,0,INIT)   STEP(2,3,4,0,0,0,INIT)  \
  STEP(3,4,5,1,0,0,INIT)   STEP(4,5,6,1,0,0,INIT)                           \
  STEP(5,6,7,1,1,0,INIT)   STEP(6,7,8,1,1,1,INIT)   STEP(7,8,9,1,1,2,INIT)  \
  STEP(8,9,10,1,1,3,INIT)  STEP(9,10,11,1,1,4,INIT)                         \
  STEP(10,11,12,1,1,5,INIT) STEP(11,12,13,1,1,6,INIT)                       \
  STEP(12,13,14,1,1,7,INIT)                                                 \
  STEP(13,14,15,0,0,0,INIT) STEP(14,15,16,0,0,0,INIT)                       \
  STEP(15,16,17,0,0,0,INIT) }

#define S_V16 { STAGE_BEGIN                                                 \
  STEP(0,1,2,0,0,0,0)   STEP(1,2,3,0,0,0,0)                                 \
  STEP(2,3,4,1,0,0,0)   STEP(3,4,5,1,0,0,0)                                 \
  STEP(4,5,6,1,1,0,0)   STEP(5,6,7,1,1,1,0)   STEP(6,7,8,1,1,2,0)           \
  STEP(7,8,9,1,1,3,0)   STEP(8,9,10,1,1,4,0)  STEP(9,10,11,1,1,5,0)         \
  STEP(10,11,12,1,1,6,0) STEP(11,12,13,1,1,7,0)                             \
  STEP(12,13,14,0,0,0,0) STEP(13,14,15,0,0,0,0) }

#define S_V14 { STAGE_BEGIN                                                 \
  STEP(0,1,2,0,0,0,0)                                                       \
  STEP(1,2,3,1,0,0,0)   STEP(2,3,4,1,0,0,0)                                 \
  STEP(3,4,5,1,1,0,0)   STEP(4,5,6,1,1,1,0)   STEP(5,6,7,1,1,2,0)           \
  STEP(6,7,8,1,1,3,0)   STEP(7,8,9,1,1,4,0)   STEP(8,9,10,1,1,5,0)          \
  STEP(9,10,11,1,1,6,0) STEP(10,11,12,1,1,7,0)                              \
  STEP(11,12,13,0,0,0,0) }

#define S_V12 { STAGE_BEGIN                                                 \
  STEP(0,1,2,1,0,0,0)   STEP(1,2,3,1,0,0,0)                                 \
  STEP(2,3,4,1,1,0,0)   STEP(3,4,5,1,1,1,0)   STEP(4,5,6,1,1,2,0)           \
  STEP(5,6,7,1,1,3,0)   STEP(6,7,8,1,1,4,0)   STEP(7,8,9,1,1,5,0)           \
  STEP(8,9,10,1,1,6,0)  STEP(9,10,11,1,1,7,0) }

#define DECLF(i) uint32_t F##i##a, F##i##b;

#define COMMON_SETUP                                                        \
  const int l = threadIdx.x & 63;                                           \
  const int wid = threadIdx.x >> 6;                                         \
  const int w = blockIdx.x;                                                 \
  const int y0 = (blockIdx.y * 4 + wid) * RV;                               \
  const size_t base = (size_t)blockIdx.z * (size_t)(W * H);                 \
  const int rx = 208 * w - 8 + 4 * l;                                       \
  const int cq = min(max(rx, 0), W - 4);                                    \
  const bool mL = (rx == 0);                                                \
  const bool mR = (rx == W - 4);                                            \
  const bool top = (y0 == 0);                                               \
  const bool bot = (y0 + RV == H);                                          \
  const int wend = min(208 * (w + 1), W);                                   \
  const bool wr = (rx >= 208 * w) && (rx < wend);                           \
  const uint32_t ONE2 = 0x3C003C00u;

#define DECL_ALL_F18                                                        \
  DECLF(0) DECLF(1) DECLF(2) DECLF(3) DECLF(4) DECLF(5) DECLF(6) DECLF(7)   \
  DECLF(8) DECLF(9) DECLF(10) DECLF(11) DECLF(12) DECLF(13) DECLF(14)       \
  DECLF(15) DECLF(16) DECLF(17)
#define DECL_ALL_Q                                                          \
  uint32_t Q0a, Q0b, Q1a, Q1b, Q2a, Q2b, Q3a, Q3b;                          \
  uint32_t Q4a, Q4b, Q5a, Q5b, Q6a, Q6b, Q7a, Q7b;

#define LOADQ_ALL(qp)                                                       \
  { const uint2 v = *(const uint2*)(qp + base + (size_t)(y0 + 0) * W + cq); \
    Q0a = v.x; Q0b = v.y; }                                                 \
  { const uint2 v = *(const uint2*)(qp + base + (size_t)(y0 + 1) * W + cq); \
    Q1a = v.x; Q1b = v.y; }                                                 \
  { const uint2 v = *(const uint2*)(qp + base + (size_t)(y0 + 2) * W + cq); \
    Q2a = v.x; Q2b = v.y; }                                                 \
  { const uint2 v = *(const uint2*)(qp + base + (size_t)(y0 + 3) * W + cq); \
    Q3a = v.x; Q3b = v.y; }                                                 \
  { const uint2 v = *(const uint2*)(qp + base + (size_t)(y0 + 4) * W + cq); \
    Q4a = v.x; Q4b = v.y; }                                                 \
  { const uint2 v = *(const uint2*)(qp + base + (size_t)(y0 + 5) * W + cq); \
    Q5a = v.x; Q5b = v.y; }                                                 \
  { const uint2 v = *(const uint2*)(qp + base + (size_t)(y0 + 6) * W + cq); \
    Q6a = v.x; Q6b = v.y; }                                                 \
  { const uint2 v = *(const uint2*)(qp + base + (size_t)(y0 + 7) * W + cq); \
    Q7a = v.x; Q7b = v.y; }

#define STOREQ16_ALL(qp)                                                    \
  *(uint2*)(qp + base + (size_t)(y0 + 0) * W + rx) = make_uint2(Q0a, Q0b);  \
  *(uint2*)(qp + base + (size_t)(y0 + 1) * W + rx) = make_uint2(Q1a, Q1b);  \
  *(uint2*)(qp + base + (size_t)(y0 + 2) * W + rx) = make_uint2(Q2a, Q2b);  \
  *(uint2*)(qp + base + (size_t)(y0 + 3) * W + rx) = make_uint2(Q3a, Q3b);  \
  *(uint2*)(qp + base + (size_t)(y0 + 4) * W + rx) = make_uint2(Q4a, Q4b);  \
  *(uint2*)(qp + base + (size_t)(y0 + 5) * W + rx) = make_uint2(Q5a, Q5b);  \
  *(uint2*)(qp + base + (size_t)(y0 + 6) * W + rx) = make_uint2(Q6a, Q6b);  \
  *(uint2*)(qp + base + (size_t)(y0 + 7) * W + rx) = make_uint2(Q7a, Q7b);

// After S stages with HALO=S+1, output row y0+k sits at F(1+k).
#define STOREE_ALL(ep)                                                      \
  *(uint2*)(ep + base + (size_t)(y0 + 0) * W + rx) = make_uint2(F1a, F1b);  \
  *(uint2*)(ep + base + (size_t)(y0 + 1) * W + rx) = make_uint2(F2a, F2b);  \
  *(uint2*)(ep + base + (size_t)(y0 + 2) * W + rx) = make_uint2(F3a, F3b);  \
  *(uint2*)(ep + base + (size_t)(y0 + 3) * W + rx) = make_uint2(F4a, F4b);  \
  *(uint2*)(ep + base + (size_t)(y0 + 4) * W + rx) = make_uint2(F5a, F5b);  \
  *(uint2*)(ep + base + (size_t)(y0 + 5) * W + rx) = make_uint2(F6a, F6b);  \
  *(uint2*)(ep + base + (size_t)(y0 + 6) * W + rx) = make_uint2(F7a, F7b);  \
  *(uint2*)(ep + base + (size_t)(y0 + 7) * W + rx) = make_uint2(F8a, F8b);

// Launch 1 (S=4, HALO=5, R=18): img f32 -> E4 f16 + q16 (init).
__global__ __launch_bounds__(256) void skelA(const float* __restrict__ in,
                                             uint16_t* __restrict__ e4,
                                             uint16_t* __restrict__ q16) {
  COMMON_SETUP
  DECL_ALL_F18
  DECL_ALL_Q
#define LOADROW(i) {                                                        \
    const int gy = min(max(y0 - 5 + i, 0), H - 1);                          \
    const float4 v = *(const float4*)(in + base + (size_t)gy * W + cq);     \
    F##i##a = PK(v.x, v.y); F##i##b = PK(v.z, v.w); }
  LOADROW(0) LOADROW(1) LOADROW(2) LOADROW(3) LOADROW(4) LOADROW(5)
  LOADROW(6) LOADROW(7) LOADROW(8) LOADROW(9) LOADROW(10) LOADROW(11)
  LOADROW(12) LOADROW(13) LOADROW(14) LOADROW(15) LOADROW(16) LOADROW(17)
#undef LOADROW
  S_V18(1) S_V16 S_V14 S_V12
  if (wr) {
    STOREQ16_ALL(q16)
    STOREE_ALL(e4)
  }
}

// Launch 2 (S=4, HALO=5, R=18): E4 + q16 -> E8 + q16 (in-place q).
__global__ __launch_bounds__(256) void skelB(const uint16_t* __restrict__ e4,
                                             uint16_t* __restrict__ e8,
                                             uint16_t* __restrict__ q16) {
  COMMON_SETUP
  DECL_ALL_F18
  DECL_ALL_Q
#define LOADROW(i) {                                                        \
    const int gy = min(max(y0 - 5 + i, 0), H - 1);                          \
    const uint2 v = *(const uint2*)(e4 + base + (size_t)gy * W + cq);       \
    F##i##a = v.x; F##i##b = v.y; }
  LOADROW(0) LOADROW(1) LOADROW(2) LOADROW(3) LOADROW(4) LOADROW(5)
  LOADROW(6) LOADROW(7) LOADROW(8) LOADROW(9) LOADROW(10) LOADROW(11)
  LOADROW(12) LOADROW(13) LOADROW(14) LOADROW(15) LOADROW(16) LOADROW(17)
#undef LOADROW
  LOADQ_ALL(q16)
  S_V18(0) S_V16 S_V14 S_V12
  if (wr) {
    STOREQ16_ALL(q16)
    STOREE_ALL(e8)
  }
}

// Launch 3 (S=3, HALO=4, R=16): E8 + q16 -> skel f32.
__global__ __launch_bounds__(256) void skelC(const uint16_t* __restrict__ e8,
                                             const uint16_t* __restrict__ q16,
                                             float* __restrict__ skel) {
  COMMON_SETUP
  DECLF(0) DECLF(1) DECLF(2) DECLF(3) DECLF(4) DECLF(5) DECLF(6) DECLF(7)
  DECLF(8) DECLF(9) DECLF(10) DECLF(11) DECLF(12) DECLF(13) DECLF(14)
  DECLF(15)
  DECL_ALL_Q
#define LOADROW(i) {                                                        \
    const int gy = min(max(y0 - 4 + i, 0), H - 1);                          \
    const uint2 v = *(const uint2*)(e8 + base + (size_t)gy * W + cq);       \
    F##i##a = v.x; F##i##b = v.y; }
  LOADROW(0) LOADROW(1) LOADROW(2) LOADROW(3) LOADROW(4) LOADROW(5)
  LOADROW(6) LOADROW(7) LOADROW(8) LOADROW(9) LOADROW(10) LOADROW(11)
  LOADROW(12) LOADROW(13) LOADROW(14) LOADROW(15)
#undef LOADROW
  LOADQ_ALL(q16)
  S_V16 S_V14 S_V12
  if (wr) {
#define STOREQ(k) {                                                         \
      float4 s;                                                             \
      s.x = 1.0f - CVTLO(Q##k##a); s.y = 1.0f - CVTHI(Q##k##a);             \
      s.z = 1.0f - CVTLO(Q##k##b); s.w = 1.0f - CVTHI(Q##k##b);             \
      *(float4*)(skel + base + (size_t)(y0 + k) * W + rx) = s; }
    STOREQ(0) STOREQ(1) STOREQ(2) STOREQ(3)
    STOREQ(4) STOREQ(5) STOREQ(6) STOREQ(7)
#undef STOREQ
  }
}

extern "C" void kernel_launch(void* const* d_in, const int* in_sizes, int n_in,
                              void* d_out, int out_size, void* d_ws,
                              size_t ws_size, hipStream_t stream) {
  const float* img = (const float*)d_in[0];
  float* skel = (float*)d_out;
  const size_t NPIX = (size_t)NBATCH * W * H;
  uint16_t* E4 = (uint16_t*)d_ws;       // 32 MiB
  uint16_t* E8 = E4 + NPIX;             // 32 MiB
  uint16_t* Q = E8 + NPIX;              // 32 MiB (in-place across launches)

  dim3 grid(5, H / (4 * RV), NBATCH);  // 5 x 32 x 16 blocks, 256 thr
  skelA<<<grid, 256, 0, stream>>>(img, E4, Q);   // init + iters 1..3
  skelB<<<grid, 256, 0, stream>>>(E4, E8, Q);    // iters 4..7
  skelC<<<grid, 256, 0, stream>>>(E8, Q, skel);  // iters 8..10
}

// Round 16
// 108.472 us; speedup vs baseline: 1.0419x; 1.0419x over previous
//
#include <hip/hip_runtime.h>
#include <hip/hip_fp16.h>

// SoftMorphology soft-skeleton: columns-in-registers stencil, f16, DPP.
// Round-16 = round-14's verified RV=16 2-launch stage algebra, but with
// 2 COLS/LANE (one half2 reg per row) instead of 4:
//  * per-STEP instruction count ~halves (one reg chain, not two);
//  * F-state halves 60 -> 30 regs; state ~49 -> VGPR ~56-70 (r14 hit the
//    128 cap and fell to 17% occupancy; r15 proved <64 VGPR alone isn't
//    sufficient -- but here we get low VGPR AND r14's best step count);
//  * waves double (10 col-windows x 64 y-strips x 16 = 10240 = 10/SIMD
//    of work) -> smoother ramp/tail than r14's 5120.
// Geometry: wave covers 128 cols (2/lane), writes 112 (halo 8 = 4 lanes
// each side >= S+1=7); 10 windows (112x9 + 16). RV=16 rows;
// R = RV+2*(S+1) = 30/28. Launch1 S=6 (init + iters 1..5, img f32 ->
// E6 f16 + q16 f16), Launch2 S=5 (iters 6..10, E6+q16 -> skel f32).
// Verified-invariant algorithm (r5-r15): erode = min 5-pt cross, dilate =
// max 3x3 (selection => f16-exact); q = 1-s, q *= 1-relu(pm-dd).
// Borders: clamped loads = replicate guards absorbed by erode; dilate
// exact via mL/mR lane overrides + top/bot h-row swaps; DPP invalid-lane
// zeros land in the region-edge contamination margin only.
// NO arrays anywhere (r4-r8: arrays -> scratch).

#define W 1024
#define H 1024
#define NBATCH 16
#define RV 16

__device__ __forceinline__ uint32_t HMIN2(uint32_t a, uint32_t b) {
  uint32_t d;
  asm("v_pk_min_f16 %0, %1, %2" : "=v"(d) : "v"(a), "v"(b));
  return d;
}
__device__ __forceinline__ uint32_t HMAX2(uint32_t a, uint32_t b) {
  uint32_t d;
  asm("v_pk_max_f16 %0, %1, %2" : "=v"(d) : "v"(a), "v"(b));
  return d;
}
__device__ __forceinline__ uint32_t PKSUB(uint32_t a, uint32_t b) {
  uint32_t d;  // a - b (packed f16)
  asm("v_pk_add_f16 %0, %1, %2 neg_lo:[0,1] neg_hi:[0,1]"
      : "=v"(d) : "v"(a), "v"(b));
  return d;
}
__device__ __forceinline__ uint32_t PKMUL(uint32_t a, uint32_t b) {
  uint32_t d;
  asm("v_pk_mul_f16 %0, %1, %2" : "=v"(d) : "v"(a), "v"(b));
  return d;
}
__device__ __forceinline__ uint32_t PKRELU(uint32_t a) {
  uint32_t d;  // max(a, 0) packed
  asm("v_pk_max_f16 %0, %1, 0" : "=v"(d) : "v"(a));
  return d;
}
__device__ __forceinline__ uint32_t PK(float x, float y) {
  __half2 h = __floats2half2_rn(x, y);
  return *(uint32_t*)&h;
}
__device__ __forceinline__ float CVTLO(uint32_t u) {
  uint16_t t = (uint16_t)(u & 0xffffu);
  __half h = *(__half*)&t;
  return __half2float(h);
}
__device__ __forceinline__ float CVTHI(uint32_t u) {
  uint16_t t = (uint16_t)(u >> 16);
  __half h = *(__half*)&t;
  return __half2float(h);
}
// DPP wave shifts: lane i <- lane i-1 (SHUP) / lane i+1 (SHDN); invalid
// lane gets 0 (bound_ctrl) -- lands in halo contamination zone only.
__device__ __forceinline__ uint32_t SHUP(uint32_t x) {  // wave_shr:1
  return (uint32_t)__builtin_amdgcn_update_dpp(0, (int)x, 0x138, 0xf, 0xf,
                                               true);
}
__device__ __forceinline__ uint32_t SHDN(uint32_t x) {  // wave_shl:1
  return (uint32_t)__builtin_amdgcn_update_dpp(0, (int)x, 0x130, 0xf, 0xf,
                                               true);
}

// One pipeline step i (P,C,N = i-1,i,i+1): erode (row P <- min-cross of
// PM,C,N), rolling h-max, packed-f16 skel-q update for row K.
// Packing: low half = col c0, high half = col c1 (2 cols/lane).
#define STEP(P, C, N, DOH, DOU, K, INIT) {                                  \
  const uint32_t c = F##C;                                                  \
  const uint32_t n = F##N;                                                  \
  const uint32_t vm = HMIN2(HMIN2(PM, c), n);                               \
  const uint32_t t = SHUP(c);                                               \
  const uint32_t r = SHDN(c);                                               \
  const uint32_t lf = mL ? (c & 0xffffu) : (t >> 16);                       \
  const uint32_t rt = mR ? (c >> 16) : (r & 0xffffu);                       \
  const uint32_t sra = lf | (c << 16);          /* {left0, c0} */           \
  const uint32_t sla = (c >> 16) | (rt << 16);  /* {c1, right1} */          \
  const uint32_t e = HMIN2(vm, HMIN2(sra, sla));                            \
  if (DOH) {                                                                \
    const uint32_t te = SHUP(e);                                            \
    const uint32_t re = SHDN(e);                                            \
    const uint32_t elf = mL ? (e & 0xffffu) : (te >> 16);                   \
    const uint32_t ert = mR ? (e >> 16) : (re & 0xffffu);                   \
    const uint32_t esra = elf | (e << 16);                                  \
    const uint32_t esla = (e >> 16) | (ert << 16);                          \
    const uint32_t hc = HMAX2(e, HMAX2(esra, esla));                        \
    if (DOU) {                                                              \
      uint32_t ha = h2, hb = hc;                                            \
      if (K == 0 && top) { ha = h1; }                                       \
      if (K == RV - 1 && bot) { hb = h1; }                                  \
      const uint32_t dd = HMAX2(HMAX2(ha, h1), hb);                         \
      const uint32_t f = PKSUB(ONE2, PKRELU(PKSUB(PM, dd)));                \
      if (INIT) { Q##K = f; }                                               \
      else { Q##K = PKMUL(Q##K, f); }                                       \
    }                                                                       \
    h2 = h1; h1 = hc;                                                       \
  }                                                                         \
  F##P = e;                                                                 \
  PM = c;                                                                   \
}

#define STAGE_BEGIN uint32_t PM = F0, h1 = 0, h2 = 0;

// RV=16 stage bodies by valid-row count V; HT = (V-RV-2)/2 = HALO-T.
// DOH i in [HT, HT+RV+1], DOU i in [HT+2, HT+RV+1], K = i-2-HT.
// (Same window algebra as round 14, verified.)
#define S_V30(INIT) { STAGE_BEGIN                                           \
  STEP(0,1,2,0,0,0,INIT)   STEP(1,2,3,0,0,0,INIT)   STEP(2,3,4,0,0,0,INIT)  \
  STEP(3,4,5,0,0,0,INIT)   STEP(4,5,6,0,0,0,INIT)                           \
  STEP(5,6,7,1,0,0,INIT)   STEP(6,7,8,1,0,0,INIT)                           \
  STEP(7,8,9,1,1,0,INIT)   STEP(8,9,10,1,1,1,INIT)                          \
  STEP(9,10,11,1,1,2,INIT) STEP(10,11,12,1,1,3,INIT)                        \
  STEP(11,12,13,1,1,4,INIT) STEP(12,13,14,1,1,5,INIT)                       \
  STEP(13,14,15,1,1,6,INIT) STEP(14,15,16,1,1,7,INIT)                       \
  STEP(15,16,17,1,1,8,INIT) STEP(16,17,18,1,1,9,INIT)                       \
  STEP(17,18,19,1,1,10,INIT) STEP(18,19,20,1,1,11,INIT)                     \
  STEP(19,20,21,1,1,12,INIT) STEP(20,21,22,1,1,13,INIT)                     \
  STEP(21,22,23,1,1,14,INIT) STEP(22,23,24,1,1,15,INIT)                     \
  STEP(23,24,25,0,0,0,INIT) STEP(24,25,26,0,0,0,INIT)                       \
  STEP(25,26,27,0,0,0,INIT) STEP(26,27,28,0,0,0,INIT)                       \
  STEP(27,28,29,0,0,0,INIT) }

#define S_V28 { STAGE_BEGIN                                                 \
  STEP(0,1,2,0,0,0,0)   STEP(1,2,3,0,0,0,0)   STEP(2,3,4,0,0,0,0)           \
  STEP(3,4,5,0,0,0,0)                                                       \
  STEP(4,5,6,1,0,0,0)   STEP(5,6,7,1,0,0,0)                                 \
  STEP(6,7,8,1,1,0,0)   STEP(7,8,9,1,1,1,0)   STEP(8,9,10,1,1,2,0)          \
  STEP(9,10,11,1,1,3,0) STEP(10,11,12,1,1,4,0) STEP(11,12,13,1,1,5,0)       \
  STEP(12,13,14,1,1,6,0) STEP(13,14,15,1,1,7,0) STEP(14,15,16,1,1,8,0)      \
  STEP(15,16,17,1,1,9,0) STEP(16,17,18,1,1,10,0) STEP(17,18,19,1,1,11,0)    \
  STEP(18,19,20,1,1,12,0) STEP(19,20,21,1,1,13,0) STEP(20,21,22,1,1,14,0)   \
  STEP(21,22,23,1,1,15,0)                                                   \
  STEP(22,23,24,0,0,0,0) STEP(23,24,25,0,0,0,0) STEP(24,25,26,0,0,0,0)      \
  STEP(25,26,27,0,0,0,0) }

#define S_V26 { STAGE_BEGIN                                                 \
  STEP(0,1,2,0,0,0,0)   STEP(1,2,3,0,0,0,0)   STEP(2,3,4,0,0,0,0)           \
  STEP(3,4,5,1,0,0,0)   STEP(4,5,6,1,0,0,0)                                 \
  STEP(5,6,7,1,1,0,0)   STEP(6,7,8,1,1,1,0)   STEP(7,8,9,1,1,2,0)           \
  STEP(8,9,10,1,1,3,0)  STEP(9,10,11,1,1,4,0) STEP(10,11,12,1,1,5,0)        \
  STEP(11,12,13,1,1,6,0) STEP(12,13,14,1,1,7,0) STEP(13,14,15,1,1,8,0)      \
  STEP(14,15,16,1,1,9,0) STEP(15,16,17,1,1,10,0) STEP(16,17,18,1,1,11,0)    \
  STEP(17,18,19,1,1,12,0) STEP(18,19,20,1,1,13,0) STEP(19,20,21,1,1,14,0)   \
  STEP(20,21,22,1,1,15,0)                                                   \
  STEP(21,22,23,0,0,0,0) STEP(22,23,24,0,0,0,0) STEP(23,24,25,0,0,0,0) }

#define S_V24 { STAGE_BEGIN                                                 \
  STEP(0,1,2,0,0,0,0)   STEP(1,2,3,0,0,0,0)                                 \
  STEP(2,3,4,1,0,0,0)   STEP(3,4,5,1,0,0,0)                                 \
  STEP(4,5,6,1,1,0,0)   STEP(5,6,7,1,1,1,0)   STEP(6,7,8,1,1,2,0)           \
  STEP(7,8,9,1,1,3,0)   STEP(8,9,10,1,1,4,0)  STEP(9,10,11,1,1,5,0)         \
  STEP(10,11,12,1,1,6,0) STEP(11,12,13,1,1,7,0) STEP(12,13,14,1,1,8,0)      \
  STEP(13,14,15,1,1,9,0) STEP(14,15,16,1,1,10,0) STEP(15,16,17,1,1,11,0)    \
  STEP(16,17,18,1,1,12,0) STEP(17,18,19,1,1,13,0) STEP(18,19,20,1,1,14,0)   \
  STEP(19,20,21,1,1,15,0)                                                   \
  STEP(20,21,22,0,0,0,0) STEP(21,22,23,0,0,0,0) }

#define S_V22 { STAGE_BEGIN                                                 \
  STEP(0,1,2,0,0,0,0)                                                       \
  STEP(1,2,3,1,0,0,0)   STEP(2,3,4,1,0,0,0)                                 \
  STEP(3,4,5,1,1,0,0)   STEP(4,5,6,1,1,1,0)   STEP(5,6,7,1,1,2,0)           \
  STEP(6,7,8,1,1,3,0)   STEP(7,8,9,1,1,4,0)   STEP(8,9,10,1,1,5,0)          \
  STEP(9,10,11,1,1,6,0) STEP(10,11,12,1,1,7,0) STEP(11,12,13,1,1,8,0)       \
  STEP(12,13,14,1,1,9,0) STEP(13,14,15,1,1,10,0) STEP(14,15,16,1,1,11,0)    \
  STEP(15,16,17,1,1,12,0) STEP(16,17,18,1,1,13,0) STEP(17,18,19,1,1,14,0)   \
  STEP(18,19,20,1,1,15,0)                                                   \
  STEP(19,20,21,0,0,0,0) }

#define S_V20 { STAGE_BEGIN                                                 \
  STEP(0,1,2,1,0,0,0)   STEP(1,2,3,1,0,0,0)                                 \
  STEP(2,3,4,1,1,0,0)   STEP(3,4,5,1,1,1,0)   STEP(4,5,6,1,1,2,0)           \
  STEP(5,6,7,1,1,3,0)   STEP(6,7,8,1,1,4,0)   STEP(7,8,9,1,1,5,0)           \
  STEP(8,9,10,1,1,6,0)  STEP(9,10,11,1,1,7,0) STEP(10,11,12,1,1,8,0)        \
  STEP(11,12,13,1,1,9,0) STEP(12,13,14,1,1,10,0) STEP(13,14,15,1,1,11,0)    \
  STEP(14,15,16,1,1,12,0) STEP(15,16,17,1,1,13,0) STEP(16,17,18,1,1,14,0)   \
  STEP(17,18,19,1,1,15,0) }

#define DECLF(i) uint32_t F##i;

#define COMMON_SETUP                                                        \
  const int l = threadIdx.x & 63;                                           \
  const int wid = threadIdx.x >> 6;                                         \
  const int w = blockIdx.x;                                                 \
  const int y0 = (blockIdx.y * 2 + wid) * RV;                               \
  const size_t base = (size_t)blockIdx.z * (size_t)(W * H);                 \
  const int rx = 112 * w - 8 + 2 * l;                                       \
  const int cq = min(max(rx, 0), W - 2);                                    \
  const bool mL = (rx == 0);                                                \
  const bool mR = (rx == W - 2);                                            \
  const bool top = (y0 == 0);                                               \
  const bool bot = (y0 + RV == H);                                          \
  const int wend = min(112 * (w + 1), W);                                   \
  const bool wr = (rx >= 112 * w) && (rx < wend);                           \
  const uint32_t ONE2 = 0x3C003C00u;

// Launch 1 (S=6, HALO=7, R=30): img f32 -> E6 f16 + q16 f16 (init).
__global__ __launch_bounds__(128) void skel6(const float* __restrict__ in,
                                             uint16_t* __restrict__ e16,
                                             uint16_t* __restrict__ q16) {
  COMMON_SETUP
  DECLF(0) DECLF(1) DECLF(2) DECLF(3) DECLF(4) DECLF(5) DECLF(6) DECLF(7)
  DECLF(8) DECLF(9) DECLF(10) DECLF(11) DECLF(12) DECLF(13) DECLF(14)
  DECLF(15) DECLF(16) DECLF(17) DECLF(18) DECLF(19) DECLF(20) DECLF(21)
  DECLF(22) DECLF(23) DECLF(24) DECLF(25) DECLF(26) DECLF(27) DECLF(28)
  DECLF(29)
  uint32_t Q0, Q1, Q2, Q3, Q4, Q5, Q6, Q7;
  uint32_t Q8, Q9, Q10, Q11, Q12, Q13, Q14, Q15;

#define LOADROW(i) {                                                        \
    const int gy = min(max(y0 - 7 + i, 0), H - 1);                          \
    const float2 v = *(const float2*)(in + base + (size_t)gy * W + cq);     \
    F##i = PK(v.x, v.y); }
  LOADROW(0) LOADROW(1) LOADROW(2) LOADROW(3) LOADROW(4) LOADROW(5)
  LOADROW(6) LOADROW(7) LOADROW(8) LOADROW(9) LOADROW(10) LOADROW(11)
  LOADROW(12) LOADROW(13) LOADROW(14) LOADROW(15) LOADROW(16) LOADROW(17)
  LOADROW(18) LOADROW(19) LOADROW(20) LOADROW(21) LOADROW(22) LOADROW(23)
  LOADROW(24) LOADROW(25) LOADROW(26) LOADROW(27) LOADROW(28) LOADROW(29)
#undef LOADROW

  S_V30(1) S_V28 S_V26 S_V24 S_V22 S_V20

  if (wr) {
#define STOREQ(k)                                                           \
    *(uint32_t*)(q16 + base + (size_t)(y0 + k) * W + rx) = Q##k;
    STOREQ(0) STOREQ(1) STOREQ(2) STOREQ(3)
    STOREQ(4) STOREQ(5) STOREQ(6) STOREQ(7)
    STOREQ(8) STOREQ(9) STOREQ(10) STOREQ(11)
    STOREQ(12) STOREQ(13) STOREQ(14) STOREQ(15)
#undef STOREQ
    // E6 rows y0+k live in F(1+k) after 6 window shifts.
#define STOREE(k, j)                                                        \
    *(uint32_t*)(e16 + base + (size_t)(y0 + k) * W + rx) = F##j;
    STOREE(0, 1) STOREE(1, 2) STOREE(2, 3) STOREE(3, 4)
    STOREE(4, 5) STOREE(5, 6) STOREE(6, 7) STOREE(7, 8)
    STOREE(8, 9) STOREE(9, 10) STOREE(10, 11) STOREE(11, 12)
    STOREE(12, 13) STOREE(13, 14) STOREE(14, 15) STOREE(15, 16)
#undef STOREE
  }
}

// Launch 2 (S=5, HALO=6, R=28): E6 f16 + q16 -> skel f32.
__global__ __launch_bounds__(128) void skel5(const uint16_t* __restrict__ e16,
                                             const uint16_t* __restrict__ q16,
                                             float* __restrict__ skel) {
  COMMON_SETUP
  DECLF(0) DECLF(1) DECLF(2) DECLF(3) DECLF(4) DECLF(5) DECLF(6) DECLF(7)
  DECLF(8) DECLF(9) DECLF(10) DECLF(11) DECLF(12) DECLF(13) DECLF(14)
  DECLF(15) DECLF(16) DECLF(17) DECLF(18) DECLF(19) DECLF(20) DECLF(21)
  DECLF(22) DECLF(23) DECLF(24) DECLF(25) DECLF(26) DECLF(27)
  uint32_t Q0, Q1, Q2, Q3, Q4, Q5, Q6, Q7;
  uint32_t Q8, Q9, Q10, Q11, Q12, Q13, Q14, Q15;

#define LOADROW(i) {                                                        \
    const int gy = min(max(y0 - 6 + i, 0), H - 1);                          \
    F##i = *(const uint32_t*)(e16 + base + (size_t)gy * W + cq); }
  LOADROW(0) LOADROW(1) LOADROW(2) LOADROW(3) LOADROW(4) LOADROW(5)
  LOADROW(6) LOADROW(7) LOADROW(8) LOADROW(9) LOADROW(10) LOADROW(11)
  LOADROW(12) LOADROW(13) LOADROW(14) LOADROW(15) LOADROW(16) LOADROW(17)
  LOADROW(18) LOADROW(19) LOADROW(20) LOADROW(21) LOADROW(22) LOADROW(23)
  LOADROW(24) LOADROW(25) LOADROW(26) LOADROW(27)
#undef LOADROW

#define LOADQ(k)                                                            \
  Q##k = *(const uint32_t*)(q16 + base + (size_t)(y0 + k) * W + cq);
  LOADQ(0) LOADQ(1) LOADQ(2) LOADQ(3) LOADQ(4) LOADQ(5) LOADQ(6) LOADQ(7)
  LOADQ(8) LOADQ(9) LOADQ(10) LOADQ(11) LOADQ(12) LOADQ(13) LOADQ(14)
  LOADQ(15)
#undef LOADQ

  S_V28 S_V26 S_V24 S_V22 S_V20

  if (wr) {
#define STOREQ(k) {                                                         \
      float2 s;                                                             \
      s.x = 1.0f - CVTLO(Q##k);                                             \
      s.y = 1.0f - CVTHI(Q##k);                                             \
      *(float2*)(skel + base + (size_t)(y0 + k) * W + rx) = s; }
    STOREQ(0) STOREQ(1) STOREQ(2) STOREQ(3)
    STOREQ(4) STOREQ(5) STOREQ(6) STOREQ(7)
    STOREQ(8) STOREQ(9) STOREQ(10) STOREQ(11)
    STOREQ(12) STOREQ(13) STOREQ(14) STOREQ(15)
#undef STOREQ
  }
}

extern "C" void kernel_launch(void* const* d_in, const int* in_sizes, int n_in,
                              void* d_out, int out_size, void* d_ws,
                              size_t ws_size, hipStream_t stream) {
  const float* img = (const float*)d_in[0];
  float* skel = (float*)d_out;
  const size_t NPIX = (size_t)NBATCH * W * H;
  uint16_t* E = (uint16_t*)d_ws;        // 32 MiB f16 E6
  uint16_t* Q = E + NPIX;               // 32 MiB f16 q (skel complement)

  dim3 grid(10, H / (2 * RV), NBATCH);  // 10 x 32 x 16 blocks, 128 thr
  skel6<<<grid, 128, 0, stream>>>(img, E, Q);
  skel5<<<grid, 128, 0, stream>>>(E, Q, skel);
}